// Round 6
// baseline (77.124 us; speedup 1.0000x reference)
//
#include <hip/hip_runtime.h>
#include <hip/hip_cooperative_groups.h>
#include <math.h>

namespace cg = cooperative_groups;

#define B_SZ   512
#define M_MIX  32
#define D_DIM  1024
#define T_MAX  4096
#define P3M    96            // 3 * M_MIX
#define KS     16            // split-K chunks
#define ROWS   16            // batch rows per phase-1 block
#define CHUNK  (D_DIM / KS)  // 64
#define C4     (CHUNK / 4)   // 16
#define RH     (ROWS / 2)    // 8 rows per compute thread
#define NRG    (B_SZ / ROWS) // 32 row-groups

// ---------------------------------------------------------------------------
// Cooperative single-node kernel. 512 blocks x 256 threads = 2 blocks/CU,
// all co-resident (cooperative launch requirement).
//   Phase 1: block p = (rg = p&31, ks = p>>5) computes split-K partials
//            ws[ks][b][j] for its 16 rows (identical math to round-4 params).
//   grid.sync() -- runtime grid barrier with device-scope fencing.
//   Phase 2: block b computes phi + masked normalize for batch row b
//            (identical math to round-4 phi kernel, KS=16).
// ---------------------------------------------------------------------------
__global__ __launch_bounds__(256) void coop_kernel(const float* __restrict__ query,
                                                   const float* __restrict__ prev_kappa,
                                                   const float* __restrict__ W,
                                                   const float* __restrict__ bias,
                                                   const int* __restrict__ seqlen,
                                                   float* __restrict__ out,
                                                   float* __restrict__ ws)
{
    const int tid = threadIdx.x;

    // ================= phase 1: split-K params GEMM =================
    {
        __shared__ float4 sQ4[ROWS][C4];
        const int rg = blockIdx.x & (NRG - 1);
        const int ks = blockIdx.x >> 5;
        const int d0 = ks * CHUNK;

        // stage q rows (coalesced float4): 16 rows x 16 float4 = 256 threads
        {
            const int r = tid / C4, dv = tid % C4;
            sQ4[r][dv] = reinterpret_cast<const float4*>(
                query + (size_t)(rg * ROWS + r) * D_DIM + d0)[dv];
        }
        __syncthreads();

        if (tid < 2 * P3M) {
            const int j  = tid % P3M;
            const int rb = (tid / P3M) * RH;
            const float* Wp = W + (size_t)d0 * P3M + j;
            float acc[RH];
            #pragma unroll
            for (int r = 0; r < RH; ++r) acc[r] = 0.f;

            #pragma unroll 2
            for (int dq = 0; dq < C4; ++dq) {
                float4 qv[RH];
                #pragma unroll
                for (int r = 0; r < RH; ++r) qv[r] = sQ4[rb + r][dq];
                #pragma unroll
                for (int e = 0; e < 4; ++e) {
                    const float w = Wp[(size_t)(dq * 4 + e) * P3M];
                    #pragma unroll
                    for (int r = 0; r < RH; ++r) {
                        const float q = (e == 0) ? qv[r].x : (e == 1) ? qv[r].y
                                      : (e == 2) ? qv[r].z : qv[r].w;
                        acc[r] = fmaf(q, w, acc[r]);
                    }
                }
            }
            float* o = ws + ((size_t)ks * B_SZ + (size_t)(rg * ROWS + rb)) * P3M + j;
            #pragma unroll
            for (int r = 0; r < RH; ++r) o[(size_t)r * P3M] = acc[r];
        }
    }

    // ============== grid-wide barrier (device-scope fenced) ==============
    cg::this_grid().sync();

    // ================= phase 2: phi + masked normalize =================
    {
        __shared__ float sA[M_MIX];   // alpha
        __shared__ float sC[M_MIX];   // -beta * log2(e)
        __shared__ float sK[M_MIX];   // kappa
        __shared__ float sR[M_MIX];   // half-width sqrt(37/beta)
        __shared__ float sRange[2];
        __shared__ float sRed[4];

        const int b = blockIdx.x;

        if (tid < P3M) {
            float p = bias[tid];
            #pragma unroll
            for (int ks = 0; ks < KS; ++ks)
                p += ws[((size_t)ks * B_SZ + (size_t)b) * P3M + tid];
            if (tid < M_MIX) {
                sA[tid] = __expf(p);
            } else if (tid < 2 * M_MIX) {
                const float be = __expf(p);
                sC[tid - M_MIX] = -be * 1.44269504f;
                sR[tid - M_MIX] = 6.0827625f * __frsqrt_rn(be);   // sqrt(37/beta)
            } else {
                const float ka = prev_kappa[(size_t)b * M_MIX + (tid - 2 * M_MIX)] + __expf(p);
                sK[tid - 2 * M_MIX] = ka;
                out[(size_t)B_SZ * T_MAX + (size_t)b * M_MIX + (tid - 2 * M_MIX)] = ka;
            }
        }
        __syncthreads();

        // parallel window reduce: 64 lanes, mixtures duplicated (m = tid&31)
        if (tid < 64) {
            const int m = tid & 31;
            float lo = sK[m] - sR[m];
            float hi = sK[m] + sR[m];
            #pragma unroll
            for (int off = 32; off >= 1; off >>= 1) {
                lo = fminf(lo, __shfl_xor(lo, off));
                hi = fmaxf(hi, __shfl_xor(hi, off));
            }
            if (tid == 0) { sRange[0] = lo; sRange[1] = hi; }
        }
        __syncthreads();

        const float gmin = sRange[0], gmax = sRange[1];
        const float tf = (float)tid;
        const int wbase = tid & ~63;

        float acc[16];
        #pragma unroll
        for (int i = 0; i < 16; ++i) acc[i] = 0.f;

        #pragma unroll
        for (int i = 0; i < 16; ++i) {
            const float wlo = (float)(wbase + i * 256);
            if (gmax >= wlo && gmin <= wlo + 63.0f) {   // wave-uniform skip
                const float t = tf + (float)(i * 256);
                #pragma unroll 4
                for (int m = 0; m < M_MIX; ++m) {
                    const float d = sK[m] - t;
                    acc[i] += sA[m] * exp2f(sC[m] * d * d);
                }
            }
        }

        const int L = seqlen[b];
        float s = 0.f;
        #pragma unroll
        for (int i = 0; i < 16; ++i) {
            const int t = tid + i * 256;
            if (t >= L) acc[i] = 0.f;
            s += acc[i];
        }
        #pragma unroll
        for (int off = 32; off >= 1; off >>= 1) s += __shfl_xor(s, off);
        if ((tid & 63) == 0) sRed[tid >> 6] = s;
        __syncthreads();
        const float invn = 1.0f / (sRed[0] + sRed[1] + sRed[2] + sRed[3] + 1e-8f);

        float* ob = out + (size_t)b * T_MAX;
        #pragma unroll
        for (int i = 0; i < 16; ++i)
            __builtin_nontemporal_store(acc[i] * invn, ob + tid + i * 256);
    }
}

// ---------------- fallback: round-4 two-kernel path ----------------
__global__ __launch_bounds__(256) void params_kernel_fb(const float* __restrict__ query,
                                                        const float* __restrict__ W,
                                                        float* __restrict__ ws)
{
    __shared__ float4 sQ4[ROWS][C4];
    const int rg  = blockIdx.x;
    const int ks  = blockIdx.y;
    const int tid = threadIdx.x;
    const int d0  = ks * CHUNK;
    {
        const int r = tid / C4, dv = tid % C4;
        sQ4[r][dv] = reinterpret_cast<const float4*>(
            query + (size_t)(rg * ROWS + r) * D_DIM + d0)[dv];
    }
    __syncthreads();
    if (tid < 2 * P3M) {
        const int j  = tid % P3M;
        const int rb = (tid / P3M) * RH;
        const float* Wp = W + (size_t)d0 * P3M + j;
        float acc[RH];
        #pragma unroll
        for (int r = 0; r < RH; ++r) acc[r] = 0.f;
        #pragma unroll 2
        for (int dq = 0; dq < C4; ++dq) {
            float4 qv[RH];
            #pragma unroll
            for (int r = 0; r < RH; ++r) qv[r] = sQ4[rb + r][dq];
            #pragma unroll
            for (int e = 0; e < 4; ++e) {
                const float w = Wp[(size_t)(dq * 4 + e) * P3M];
                #pragma unroll
                for (int r = 0; r < RH; ++r) {
                    const float q = (e == 0) ? qv[r].x : (e == 1) ? qv[r].y
                                  : (e == 2) ? qv[r].z : qv[r].w;
                    acc[r] = fmaf(q, w, acc[r]);
                }
            }
        }
        float* o = ws + ((size_t)ks * B_SZ + (size_t)(rg * ROWS + rb)) * P3M + j;
        #pragma unroll
        for (int r = 0; r < RH; ++r) o[(size_t)r * P3M] = acc[r];
    }
}

__global__ __launch_bounds__(256) void phi_kernel_fb(const float* __restrict__ ws,
                                                     const float* __restrict__ bias,
                                                     const float* __restrict__ prev_kappa,
                                                     const int* __restrict__ seqlen,
                                                     float* __restrict__ out)
{
    __shared__ float sA[M_MIX], sC[M_MIX], sK[M_MIX], sR[M_MIX];
    __shared__ float sRange[2], sRed[4];
    const int b = blockIdx.x, tid = threadIdx.x;
    if (tid < P3M) {
        float p = bias[tid];
        #pragma unroll
        for (int ks = 0; ks < KS; ++ks)
            p += ws[((size_t)ks * B_SZ + (size_t)b) * P3M + tid];
        if (tid < M_MIX) sA[tid] = __expf(p);
        else if (tid < 2 * M_MIX) {
            const float be = __expf(p);
            sC[tid - M_MIX] = -be * 1.44269504f;
            sR[tid - M_MIX] = 6.0827625f * __frsqrt_rn(be);
        } else {
            const float ka = prev_kappa[(size_t)b * M_MIX + (tid - 2 * M_MIX)] + __expf(p);
            sK[tid - 2 * M_MIX] = ka;
            out[(size_t)B_SZ * T_MAX + (size_t)b * M_MIX + (tid - 2 * M_MIX)] = ka;
        }
    }
    __syncthreads();
    if (tid < 64) {
        const int m = tid & 31;
        float lo = sK[m] - sR[m], hi = sK[m] + sR[m];
        #pragma unroll
        for (int off = 32; off >= 1; off >>= 1) {
            lo = fminf(lo, __shfl_xor(lo, off));
            hi = fmaxf(hi, __shfl_xor(hi, off));
        }
        if (tid == 0) { sRange[0] = lo; sRange[1] = hi; }
    }
    __syncthreads();
    const float gmin = sRange[0], gmax = sRange[1];
    const float tf = (float)tid;
    const int wbase = tid & ~63;
    float acc[16];
    #pragma unroll
    for (int i = 0; i < 16; ++i) acc[i] = 0.f;
    #pragma unroll
    for (int i = 0; i < 16; ++i) {
        const float wlo = (float)(wbase + i * 256);
        if (gmax >= wlo && gmin <= wlo + 63.0f) {
            const float t = tf + (float)(i * 256);
            #pragma unroll 4
            for (int m = 0; m < M_MIX; ++m) {
                const float d = sK[m] - t;
                acc[i] += sA[m] * exp2f(sC[m] * d * d);
            }
        }
    }
    const int L = seqlen[b];
    float s = 0.f;
    #pragma unroll
    for (int i = 0; i < 16; ++i) {
        const int t = tid + i * 256;
        if (t >= L) acc[i] = 0.f;
        s += acc[i];
    }
    #pragma unroll
    for (int off = 32; off >= 1; off >>= 1) s += __shfl_xor(s, off);
    if ((tid & 63) == 0) sRed[tid >> 6] = s;
    __syncthreads();
    const float invn = 1.0f / (sRed[0] + sRed[1] + sRed[2] + sRed[3] + 1e-8f);
    float* ob = out + (size_t)b * T_MAX;
    #pragma unroll
    for (int i = 0; i < 16; ++i)
        __builtin_nontemporal_store(acc[i] * invn, ob + tid + i * 256);
}

extern "C" void kernel_launch(void* const* d_in, const int* in_sizes, int n_in,
                              void* d_out, int out_size, void* d_ws, size_t ws_size,
                              hipStream_t stream) {
    const float* query = (const float*)d_in[0];
    const float* prevk = (const float*)d_in[1];
    const float* W     = (const float*)d_in[2];
    const float* bias  = (const float*)d_in[3];
    const int*   msl   = (const int*)d_in[4];
    float* out = (float*)d_out;
    float* ws  = (float*)d_ws;

    const size_t need = (size_t)KS * B_SZ * P3M * sizeof(float);
    if (ws_size >= need) {
        void* args[] = {(void*)&query, (void*)&prevk, (void*)&W, (void*)&bias,
                        (void*)&msl, (void*)&out, (void*)&ws};
        hipError_t err = hipLaunchCooperativeKernel((const void*)coop_kernel,
                                                    dim3(B_SZ), dim3(256),
                                                    args, 0, stream);
        if (err == hipSuccess) return;
        // fall through to two-kernel path if cooperative launch unsupported
        params_kernel_fb<<<dim3(NRG, KS), 256, 0, stream>>>(query, W, ws);
        phi_kernel_fb<<<B_SZ, 256, 0, stream>>>(ws, bias, prevk, msl, out);
    } else {
        params_kernel_fb<<<dim3(NRG, KS), 256, 0, stream>>>(query, W, ws);
        phi_kernel_fb<<<B_SZ, 256, 0, stream>>>(ws, bias, prevk, msl, out);
    }
}

// Round 8
// 16.659 us; speedup vs baseline: 4.6296x; 4.6296x over previous
//
#include <hip/hip_runtime.h>
#include <math.h>

#define B_SZ   512
#define M_MIX  32
#define D_DIM  1024
#define T_MAX  4096
#define P3M    96    // 3 * M_MIX

typedef float vf4 __attribute__((ext_vector_type(4)));   // native vec for nontemporal builtin

// ---------------------------------------------------------------------------
// Kernel 1: split-K partial GEMM + zero-fill of the alignments output.
// ws[ks][b][j] = sum_{d in chunk ks} q[b][d] * W[d][j]
// Grid: (B/ROWS, KS). Block: 256 threads.
// The zero-fill (8.4 MB total, 16 KB/block nontemporal vf4) is issued
// before the FMA loop so it drains underneath the L2-latency-bound W reads.
// Kernel 2 then only stores the ~1 i-block intersecting the Gaussian window.
// ---------------------------------------------------------------------------
template<int KS, int ROWS>
__global__ __launch_bounds__(256) void params_kernel(const float* __restrict__ query,
                                                     const float* __restrict__ W,
                                                     float* __restrict__ ws,
                                                     float* __restrict__ out)
{
    constexpr int CHUNK = D_DIM / KS;
    constexpr int C4    = CHUNK / 4;
    constexpr int RH    = ROWS / 2;
    __shared__ float4 sQ4[ROWS][C4];

    const int rg  = blockIdx.x;
    const int ks  = blockIdx.y;
    const int tid = threadIdx.x;
    const int d0  = ks * CHUNK;

    // stage q rows (coalesced float4)
    for (int idx = tid; idx < ROWS * C4; idx += 256) {
        const int r = idx / C4, dv = idx % C4;
        sQ4[r][dv] = reinterpret_cast<const float4*>(
            query + (size_t)(rg * ROWS + r) * D_DIM + d0)[dv];
    }

    // zero-fill this block's slice of the alignments output (streaming)
    {
        const int nb     = gridDim.x * gridDim.y;
        const int fb     = blockIdx.y * gridDim.x + blockIdx.x;
        const int perblk = (B_SZ * T_MAX / 4) / nb;          // vf4 count
        vf4* oz = reinterpret_cast<vf4*>(out) + (size_t)fb * perblk;
        const vf4 z = {0.f, 0.f, 0.f, 0.f};
        for (int i = tid; i < perblk; i += 256)
            __builtin_nontemporal_store(z, oz + i);
    }
    __syncthreads();

    if (tid < 2 * P3M) {
        const int j  = tid % P3M;
        const int rb = (tid / P3M) * RH;
        const float* Wp = W + (size_t)d0 * P3M + j;
        float acc[RH];
        #pragma unroll
        for (int r = 0; r < RH; ++r) acc[r] = 0.f;

        #pragma unroll 2
        for (int dq = 0; dq < C4; ++dq) {
            float4 qv[RH];
            #pragma unroll
            for (int r = 0; r < RH; ++r) qv[r] = sQ4[rb + r][dq];
            #pragma unroll
            for (int e = 0; e < 4; ++e) {
                const float w = Wp[(size_t)(dq * 4 + e) * P3M];
                #pragma unroll
                for (int r = 0; r < RH; ++r) {
                    const float q = (e == 0) ? qv[r].x : (e == 1) ? qv[r].y
                                  : (e == 2) ? qv[r].z : qv[r].w;
                    acc[r] = fmaf(q, w, acc[r]);
                }
            }
        }
        float* o = ws + ((size_t)ks * B_SZ + (size_t)(rg * ROWS + rb)) * P3M + j;
        #pragma unroll
        for (int r = 0; r < RH; ++r) o[(size_t)r * P3M] = acc[r];
    }
}

// ---------------------------------------------------------------------------
// Kernel 2: per-row phi + masked normalize. One block (256 thr) per batch row.
// Wave-uniform window skip prunes BOTH the Gaussian evaluation AND the output
// stores to the i-blocks intersecting [0, gmax] (alignments outside are zero
// at < e^-37 and were already zero-filled by kernel 1). Typically nI == 1.
// ---------------------------------------------------------------------------
template<int KS>
__global__ __launch_bounds__(256) void phi_kernel(const float* __restrict__ ws,
                                                  const float* __restrict__ bias,
                                                  const float* __restrict__ prev_kappa,
                                                  const int* __restrict__ seqlen,
                                                  float* __restrict__ out)
{
    __shared__ float sA[M_MIX];   // alpha
    __shared__ float sC[M_MIX];   // -beta * log2(e)
    __shared__ float sK[M_MIX];   // kappa
    __shared__ float sR[M_MIX];   // window half-width sqrt(37/beta)
    __shared__ float sRange[2];   // gmin, gmax over mixtures
    __shared__ float sRed[4];     // per-wave partial sums

    const int b   = blockIdx.x;
    const int tid = threadIdx.x;

    if (tid < P3M) {
        float p = bias[tid];
        #pragma unroll
        for (int ks = 0; ks < KS; ++ks)
            p += ws[((size_t)ks * B_SZ + (size_t)b) * P3M + tid];
        if (tid < M_MIX) {
            sA[tid] = __expf(p);
        } else if (tid < 2 * M_MIX) {
            const float be = __expf(p);
            sC[tid - M_MIX] = -be * 1.44269504f;
            sR[tid - M_MIX] = 6.0827625f * __frsqrt_rn(be);   // sqrt(37/beta)
        } else {
            const float ka = prev_kappa[(size_t)b * M_MIX + (tid - 2 * M_MIX)] + __expf(p);
            sK[tid - 2 * M_MIX] = ka;
            out[(size_t)B_SZ * T_MAX + (size_t)b * M_MIX + (tid - 2 * M_MIX)] = ka;
        }
    }
    __syncthreads();

    // parallel window reduce: 64 lanes, mixtures duplicated (m = tid&31)
    if (tid < 64) {
        const int m = tid & 31;
        float lo = sK[m] - sR[m];
        float hi = sK[m] + sR[m];
        #pragma unroll
        for (int off = 32; off >= 1; off >>= 1) {
            lo = fminf(lo, __shfl_xor(lo, off));
            hi = fmaxf(hi, __shfl_xor(hi, off));
        }
        if (tid == 0) { sRange[0] = lo; sRange[1] = hi; }
    }
    __syncthreads();

    const float gmin = sRange[0], gmax = sRange[1];
    const float tf = (float)tid;
    const int wbase = tid & ~63;   // wave's first tid

    float acc[16];
    #pragma unroll
    for (int i = 0; i < 16; ++i) acc[i] = 0.f;

    #pragma unroll
    for (int i = 0; i < 16; ++i) {
        const float wlo = (float)(wbase + i * 256);
        if (gmax >= wlo && gmin <= wlo + 63.0f) {   // wave-uniform skip
            const float t = tf + (float)(i * 256);
            #pragma unroll 4
            for (int m = 0; m < M_MIX; ++m) {
                const float d = sK[m] - t;
                acc[i] += sA[m] * exp2f(sC[m] * d * d);
            }
        }
    }

    // mask + per-thread sum
    const int L = seqlen[b];
    float s = 0.f;
    #pragma unroll
    for (int i = 0; i < 16; ++i) {
        const int t = tid + i * 256;
        if (t >= L) acc[i] = 0.f;
        s += acc[i];
    }
    #pragma unroll
    for (int off = 32; off >= 1; off >>= 1) s += __shfl_xor(s, off);
    if ((tid & 63) == 0) sRed[tid >> 6] = s;
    __syncthreads();
    const float invn = 1.0f / (sRed[0] + sRed[1] + sRed[2] + sRed[3] + 1e-8f);

    // stores: only i-blocks intersecting [0, gmax]; rest already zeroed by k1
    int nI = __float2int_rz(gmax * (1.0f / 256.0f)) + 1;
    nI = (nI < 1) ? 1 : (nI > 16) ? 16 : nI;

    float* ob = out + (size_t)b * T_MAX;
    #pragma unroll
    for (int i = 0; i < 16; ++i)
        if (i < nI)
            __builtin_nontemporal_store(acc[i] * invn, ob + tid + i * 256);
}

extern "C" void kernel_launch(void* const* d_in, const int* in_sizes, int n_in,
                              void* d_out, int out_size, void* d_ws, size_t ws_size,
                              hipStream_t stream) {
    const float* query = (const float*)d_in[0];
    const float* prevk = (const float*)d_in[1];
    const float* W     = (const float*)d_in[2];
    const float* bias  = (const float*)d_in[3];
    const int*   msl   = (const int*)d_in[4];
    float* out = (float*)d_out;
    float* ws  = (float*)d_ws;

    const size_t per_ks = (size_t)B_SZ * P3M * sizeof(float);
    if (ws_size >= 16 * per_ks) {
        params_kernel<16, 16><<<dim3(B_SZ / 16, 16), 256, 0, stream>>>(query, W, ws, out);
        phi_kernel<16><<<B_SZ, 256, 0, stream>>>(ws, bias, prevk, msl, out);
    } else if (ws_size >= 4 * per_ks) {
        params_kernel<4, 8><<<dim3(B_SZ / 8, 4), 256, 0, stream>>>(query, W, ws, out);
        phi_kernel<4><<<B_SZ, 256, 0, stream>>>(ws, bias, prevk, msl, out);
    } else {
        params_kernel<1, 4><<<dim3(B_SZ / 4, 1), 256, 0, stream>>>(query, W, ws, out);
        phi_kernel<1><<<B_SZ, 256, 0, stream>>>(ws, bias, prevk, msl, out);
    }
}

// Round 9
// 15.565 us; speedup vs baseline: 4.9549x; 1.0703x over previous
//
#include <hip/hip_runtime.h>
#include <math.h>

#define B_SZ   512
#define M_MIX  32
#define D_DIM  1024
#define T_MAX  4096
#define P3M    96            // 3 * M_MIX
#define RPB    2             // batch rows per block
#define NBLK   (B_SZ / RPB)  // 256 blocks = 1 per CU
#define NTHR   512
#define KQ     4             // in-block k-split
#define KCH    (D_DIM / KQ)  // 256

typedef float vf4 __attribute__((ext_vector_type(4)));

// ---------------------------------------------------------------------------
// Single-node fused kernel, zero cross-block deps, no workspace.
// 256 blocks x 512 threads = 1 block/CU (all CUs busy in every phase).
// Block owns RPB=2 batch rows end-to-end:
//   A) stage q[2][1024] in LDS (float4) + zero-fill its own 2 output rows
//      (nontemporal; drained at the first barrier, HBM write-out in background)
//   B) GEMM: j=0..95 x kq=0..3 (384 thr), 256-long dots, q via LDS broadcast
//   C) reduce partials + transform to alpha / -beta*log2e / kappa / radius
//   D) per-row window min/max (wave reduce, mixtures duplicated)
//   E) phi with wave-uniform window skip; stores ONLY the i-blocks
//      intersecting [0, gmax] (rest provably < e^-37 and already zeroed)
// W redundancy: 256 blocks x 384 KB = 98 MB of XCD-local L2 reads (~2.9 us)
// buys freedom from any inter-block sync (round-3/6 lesson).
// ---------------------------------------------------------------------------
__global__ __launch_bounds__(NTHR) void fused_kernel(
    const float* __restrict__ query,
    const float* __restrict__ prev_kappa,
    const float* __restrict__ W,
    const float* __restrict__ bias,
    const int* __restrict__ seqlen,
    float* __restrict__ out)
{
    __shared__ float sQ[RPB][D_DIM];      // 8 KB
    __shared__ float sP[KQ][RPB][P3M];    // 3 KB partials
    __shared__ float sA[RPB][M_MIX];      // alpha
    __shared__ float sC[RPB][M_MIX];      // -beta * log2(e)
    __shared__ float sK[RPB][M_MIX];      // kappa
    __shared__ float sR[RPB][M_MIX];      // half-width sqrt(37/beta)
    __shared__ float sRange[RPB][2];
    __shared__ float sRed[RPB][4];
    __shared__ int   sL[RPB];

    const int tid = threadIdx.x;
    const int b0  = blockIdx.x * RPB;

    // ---- A: stage q (512 thr x one float4) + zero-fill own output rows ----
    {
        const int r = tid >> 8;           // 256 float4 per row
        const int c = tid & 255;
        reinterpret_cast<float4*>(&sQ[r][0])[c] =
            reinterpret_cast<const float4*>(query + (size_t)(b0 + r) * D_DIM)[c];
    }
    if (tid < RPB) sL[tid] = seqlen[b0 + tid];
    {
        // own 2 rows = 2*4096 floats = 2048 vf4; 512 thr x 4 stores
        vf4* oz = reinterpret_cast<vf4*>(out + (size_t)b0 * T_MAX);
        const vf4 z = {0.f, 0.f, 0.f, 0.f};
        #pragma unroll
        for (int i = 0; i < 4; ++i)
            __builtin_nontemporal_store(z, oz + tid + i * NTHR);
    }
    __syncthreads();

    // ---- B: k-split dots. W coalesced over j; q via LDS broadcast ----
    if (tid < KQ * P3M) {
        const int j  = tid % P3M;
        const int kq = tid / P3M;
        const float* Wp = W + (size_t)(kq * KCH) * P3M + j;
        const float* q0 = &sQ[0][kq * KCH];
        const float* q1 = &sQ[1][kq * KCH];
        float a0 = 0.f, a1 = 0.f;
        #pragma unroll 8
        for (int d = 0; d < KCH; ++d) {
            const float w = Wp[(size_t)d * P3M];
            a0 = fmaf(q0[d], w, a0);
            a1 = fmaf(q1[d], w, a1);
        }
        sP[kq][0][j] = a0;
        sP[kq][1][j] = a1;
    }
    __syncthreads();

    // ---- C: reduce + transform (192 threads: r = tid/96, j = tid%96) ----
    if (tid < RPB * P3M) {
        const int r = tid / P3M, j = tid % P3M;
        float p = bias[j];
        #pragma unroll
        for (int kq = 0; kq < KQ; ++kq) p += sP[kq][r][j];
        const int m = j & 31;
        if (j < M_MIX) {
            sA[r][m] = __expf(p);
        } else if (j < 2 * M_MIX) {
            const float be = __expf(p);
            sC[r][m] = -be * 1.44269504f;
            sR[r][m] = 6.0827625f * __frsqrt_rn(be);   // sqrt(37/beta)
        } else {
            const float ka = prev_kappa[(size_t)(b0 + r) * M_MIX + m] + __expf(p);
            sK[r][m] = ka;
            out[(size_t)B_SZ * T_MAX + (size_t)(b0 + r) * M_MIX + m] = ka;
        }
    }
    __syncthreads();

    // ---- D: per-row window reduce; wave r handles row r ----
    if (tid < RPB * 64) {
        const int r = tid >> 6;
        const int m = tid & 31;     // mixtures duplicated across 64 lanes
        float lo = sK[r][m] - sR[r][m];
        float hi = sK[r][m] + sR[r][m];
        #pragma unroll
        for (int off = 32; off >= 1; off >>= 1) {
            lo = fminf(lo, __shfl_xor(lo, off));
            hi = fmaxf(hi, __shfl_xor(hi, off));
        }
        if ((tid & 63) == 0) { sRange[r][0] = lo; sRange[r][1] = hi; }
    }
    __syncthreads();

    // ---- E: phi for row r = tid>>8, t = (tid&255) + 256*i ----
    const int   r     = tid >> 8;
    const int   lt    = tid & 255;
    const float gmin  = sRange[r][0], gmax = sRange[r][1];
    const int   wbase = lt & ~63;
    const float tf    = (float)lt;

    float acc[16];
    #pragma unroll
    for (int i = 0; i < 16; ++i) acc[i] = 0.f;

    #pragma unroll
    for (int i = 0; i < 16; ++i) {
        const float wlo = (float)(wbase + i * 256);
        if (gmax >= wlo && gmin <= wlo + 63.0f) {   // wave-uniform skip
            const float t = tf + (float)(i * 256);
            #pragma unroll 4
            for (int m = 0; m < M_MIX; ++m) {
                const float d = sK[r][m] - t;
                acc[i] += sA[r][m] * exp2f(sC[r][m] * d * d);
            }
        }
    }

    // mask + per-thread sum
    const int L = sL[r];
    float s = 0.f;
    #pragma unroll
    for (int i = 0; i < 16; ++i) {
        const int t = lt + i * 256;
        if (t >= L) acc[i] = 0.f;
        s += acc[i];
    }
    #pragma unroll
    for (int off = 32; off >= 1; off >>= 1) s += __shfl_xor(s, off);
    if ((tid & 63) == 0) sRed[r][(tid >> 6) & 3] = s;
    __syncthreads();
    const float invn = 1.0f /
        (sRed[r][0] + sRed[r][1] + sRed[r][2] + sRed[r][3] + 1e-8f);

    // stores: only i-blocks intersecting [0, gmax]; rest already zeroed in A
    int nI = __float2int_rz(gmax * (1.0f / 256.0f)) + 1;
    nI = (nI < 1) ? 1 : (nI > 16) ? 16 : nI;

    float* ob = out + (size_t)(b0 + r) * T_MAX;
    #pragma unroll
    for (int i = 0; i < 16; ++i)
        if (i < nI)
            __builtin_nontemporal_store(acc[i] * invn, ob + lt + i * 256);
}

extern "C" void kernel_launch(void* const* d_in, const int* in_sizes, int n_in,
                              void* d_out, int out_size, void* d_ws, size_t ws_size,
                              hipStream_t stream) {
    const float* query = (const float*)d_in[0];
    const float* prevk = (const float*)d_in[1];
    const float* W     = (const float*)d_in[2];
    const float* bias  = (const float*)d_in[3];
    const int*   msl   = (const int*)d_in[4];
    float* out = (float*)d_out;
    (void)d_ws; (void)ws_size;

    fused_kernel<<<NBLK, NTHR, 0, stream>>>(query, prevk, W, bias, msl, out);
}